// Round 6
// baseline (1515.711 us; speedup 1.0000x reference)
//
#include <hip/hip_runtime.h>
#include <hip/hip_bf16.h>
#include <hip/hip_fp16.h>

// TT-chain: N=65536, L=128, D=4, R=8, O=2.
//   m = x[n,0] @ core_first[0]
//   for c in 0..125: m[l] = sum_{k,j} m[k]*cm[c,k,j,l]*x[n,c+1,j]
//   out[n,:] = sum_{k,j} m[k]*cl[k,j,:]*x[n,127,j]
// cm[:, :, 3, :] == I -> j=3 term is x.w*m[l] (exact fp32 path).
//
// R6 design: R5 (fp16 cores staged to LDS, one thread/sample) + explicit
// ONE-STEP REGISTER PIPELINE for the core constants. At 1 wave/SIMD the
// compiler's JIT ds_read scheduling exposes ~1500 cyc/step of LDS latency
// (R5: wall 2686 cyc/step vs ~900 VALU + ~290 LDS-bus). Here step s+1's 24
// ds_read_b128 are issued interleaved with step s's FMAs into the alternate
// register buffer (CA/CB ping-pong), giving every load ~1 full step of
// latency cover. x uses a 4-deep rotating float4 buffer loaded 4 steps
// ahead. Expected wall: max(VALU ~900, LDS bus/CU ~1150) cyc/step.

#define NTHREADS 256
#define CHUNK_STEPS 8
#define STEP_HALFS 192                           // k*24 + j*8 + l, j<3
#define CHUNK_HALFS (CHUNK_STEPS * STEP_HALFS)   // 1536 halfs = 3072 B
#define CHUNK_BYTES (CHUNK_HALFS * 2)

typedef __attribute__((ext_vector_type(8))) _Float16 half8;

// Pack cm[126,8,4,8] (fp32) -> cmp[c][k*24 + j*8 + l] (fp16), j<3 only.
__global__ __launch_bounds__(NTHREADS) void pack_cores_h(
    const float* __restrict__ cm, _Float16* __restrict__ cmp)
{
    int t = blockIdx.x * NTHREADS + threadIdx.x;
    if (t >= 126 * STEP_HALFS) return;
    int c = t / STEP_HALFS;
    int r = t % STEP_HALFS;   // k*24 + j*8 + l
    int k = r / 24;
    int jl = r % 24;
    int j = jl / 8;
    int l = jl % 8;
    cmp[t] = (_Float16)cm[c * 256 + k * 32 + j * 8 + l];
}

__device__ __forceinline__ void gll16(const void* g, void* l) {
    __builtin_amdgcn_global_load_lds(
        (const __attribute__((address_space(1))) unsigned int*)g,
        (__attribute__((address_space(3))) unsigned int*)l, 16, 0, 0);
}

// Load one step's 24 half8 from LDS into registers.
__device__ __forceinline__ void ld_step(half8 (&C)[24], const _Float16* bs) {
    #pragma unroll
    for (int i = 0; i < 24; ++i)
        C[i] = *reinterpret_cast<const half8*>(bs + i * 8);
}

// One recurrence step consuming C (in registers); if pf != nullptr, prefetch
// the next step's constants from LDS (pfs) into pf, interleaved per-k.
__device__ __forceinline__ void tt_step(
    float (&m)[8], const half8 (&C)[24],
    half8* pf, const _Float16* pfs, const float4 xt)
{
    float nm[8];
    #pragma unroll
    for (int l = 0; l < 8; ++l) nm[l] = xt.w * m[l];
    #pragma unroll
    for (int k = 0; k < 8; ++k) {
        if (pf) {
            pf[k * 3 + 0] = *reinterpret_cast<const half8*>(pfs + k * 24 + 0);
            pf[k * 3 + 1] = *reinterpret_cast<const half8*>(pfs + k * 24 + 8);
            pf[k * 3 + 2] = *reinterpret_cast<const half8*>(pfs + k * 24 + 16);
        }
        const float p0 = m[k] * xt.x;
        const float p1 = m[k] * xt.y;
        const float p2 = m[k] * xt.z;
        const half8 A = C[k * 3 + 0];
        const half8 B = C[k * 3 + 1];
        const half8 Cc = C[k * 3 + 2];
        #pragma unroll
        for (int l = 0; l < 8; ++l) {
            nm[l] = fmaf(p0, (float)A[l], nm[l]);
            nm[l] = fmaf(p1, (float)B[l], nm[l]);
            nm[l] = fmaf(p2, (float)Cc[l], nm[l]);
        }
    }
    #pragma unroll
    for (int l = 0; l < 8; ++l) m[l] = nm[l];
}

__global__ __launch_bounds__(NTHREADS, 1) void tt_chain_rp(
    const float* __restrict__ x,       // [N,128,4]
    const _Float16* __restrict__ cmp,  // packed fp16 cores (+pad)
    const float* __restrict__ cf,      // [4,8]
    const float* __restrict__ cl,      // [8,4,2]
    float* __restrict__ out)           // [N,2]
{
    __shared__ __align__(16) _Float16 smem[2 * CHUNK_HALFS];   // 6144 B

    const int tid = threadIdx.x;
    const int n = blockIdx.x * NTHREADS + tid;   // grid covers N exactly

    const float4* __restrict__ xr = reinterpret_cast<const float4*>(x) + (size_t)n * 128;
    const char* cmpB = reinterpret_cast<const char*>(cmp);
    char* smemB = reinterpret_cast<char*>(smem);

    const int w = tid >> 6;
    const int lanebyte = (tid & 63) * 16;

    // ---- prologue: stage chunk 0 (3072 B, waves 0..2), init m, prime x ----
    if (tid < 192) {
        gll16(cmpB + w * 1024 + lanebyte, smemB + w * 1024);
    }
    const float4 x0 = xr[0];
    float4 X[4];
    #pragma unroll
    for (int i = 0; i < 4; ++i) X[i] = xr[1 + i];

    float m[8];
    #pragma unroll
    for (int k = 0; k < 8; ++k)
        m[k] = fmaf(cf[k], x0.x,
               fmaf(cf[8 + k], x0.y,
               fmaf(cf[16 + k], x0.z, cf[24 + k] * x0.w)));

    __syncthreads();   // chunk 0 staged

    half8 CA[24], CB[24];

    // step S of chunk ch: consume X[S&3] (= x[c+1]), reload slot 4 ahead
    #define DO_STEP(CUR, PFDST, PFSRC, S) do {                       \
        const float4 xt_ = X[(S) & 3];                               \
        X[(S) & 3] = xr[ch * 8 + (S) + 5];  /* <= 124 in main loop */\
        tt_step(m, CUR, PFDST, PFSRC, xt_);                          \
    } while (0)

    // ---- chunks 0..14 ----
    for (int ch = 0; ch < 15; ++ch) {
        const int nb = (ch + 1) & 1;
        if (tid < 192) {
            gll16(cmpB + (size_t)(ch + 1) * CHUNK_BYTES + w * 1024 + lanebyte,
                  smemB + nb * CHUNK_BYTES + w * 1024);
        }
        const _Float16* B = &smem[(ch & 1) * CHUNK_HALFS];

        ld_step(CA, B);   // step ch*8 (post-barrier; ~150 cyc exposed per chunk)

        DO_STEP(CA, CB, B + 1 * STEP_HALFS, 0);
        DO_STEP(CB, CA, B + 2 * STEP_HALFS, 1);
        DO_STEP(CA, CB, B + 3 * STEP_HALFS, 2);
        DO_STEP(CB, CA, B + 4 * STEP_HALFS, 3);
        DO_STEP(CA, CB, B + 5 * STEP_HALFS, 4);
        DO_STEP(CB, CA, B + 6 * STEP_HALFS, 5);
        DO_STEP(CA, CB, B + 7 * STEP_HALFS, 6);
        DO_STEP(CB, (half8*)nullptr, (const _Float16*)nullptr, 7);

        __syncthreads();
    }
    #undef DO_STEP

    // ---- tail chunk 15: steps c = 120..125 ----
    {
        const _Float16* B = &smem[CHUNK_HALFS];   // 15 & 1 == 1
        ld_step(CA, B);

        #define DO_TAIL(CUR, PFDST, PFSRC, S) do {                   \
            const float4 xt_ = X[(S) & 3];                           \
            int ix_ = 125 + (S); if (ix_ > 127) ix_ = 127;           \
            X[(S) & 3] = xr[ix_];                                    \
            tt_step(m, CUR, PFDST, PFSRC, xt_);                      \
        } while (0)

        DO_TAIL(CA, CB, B + 1 * STEP_HALFS, 0);
        DO_TAIL(CB, CA, B + 2 * STEP_HALFS, 1);
        DO_TAIL(CA, CB, B + 3 * STEP_HALFS, 2);
        DO_TAIL(CB, CA, B + 4 * STEP_HALFS, 3);
        DO_TAIL(CA, CB, B + 5 * STEP_HALFS, 4);
        DO_TAIL(CB, (half8*)nullptr, (const _Float16*)nullptr, 5);
        #undef DO_TAIL
    }

    // ---- epilogue: x[127] sits in X[2] (loaded at step c=122) ----
    {
        const float4 xl = X[2];
        const float xj[4] = { xl.x, xl.y, xl.z, xl.w };
        float o0 = 0.f, o1 = 0.f;
        #pragma unroll
        for (int j = 0; j < 4; ++j) {
            float v0 = 0.f, v1 = 0.f;
            #pragma unroll
            for (int k = 0; k < 8; ++k) {
                v0 = fmaf(m[k], cl[k * 8 + j * 2 + 0], v0);
                v1 = fmaf(m[k], cl[k * 8 + j * 2 + 1], v1);
            }
            o0 = fmaf(xj[j], v0, o0);
            o1 = fmaf(xj[j], v1, o1);
        }
        reinterpret_cast<float2*>(out)[n] = make_float2(o0, o1);
    }
}

extern "C" void kernel_launch(void* const* d_in, const int* in_sizes, int n_in,
                              void* d_out, int out_size, void* d_ws, size_t ws_size,
                              hipStream_t stream) {
    const float* x  = (const float*)d_in[0];   // [N,128,4]
    const float* cf = (const float*)d_in[1];   // [1,4,8]
    const float* cm = (const float*)d_in[2];   // [126,8,4,8]
    const float* cl = (const float*)d_in[3];   // [8,4,2]
    float* out = (float*)d_out;                // [N,2]

    const int N = in_sizes[0] / (128 * 4);

    // packed fp16 cores: 126*192*2 = 48384 B; chunk-15 staging overreads
    // 768 B of pad (steps 126,127 never consumed).
    _Float16* cmp = (_Float16*)d_ws;

    pack_cores_h<<<(126 * STEP_HALFS + NTHREADS - 1) / NTHREADS, NTHREADS, 0, stream>>>(cm, cmp);

    tt_chain_rp<<<N / NTHREADS, NTHREADS, 0, stream>>>(x, cmp, cf, cl, out);
}